// Round 1
// baseline (65.286 us; speedup 1.0000x reference)
//
#include <hip/hip_runtime.h>

// softmax(ALPHA*|x-bins|) over K=32 bins, plus weighted-sum code.
// Memory-bound: 285 MB traffic, floor ~45us at 6.3 TB/s.
// Layout: thread owns 4 consecutive k's (one float4 of soft_assignment);
// 8 threads per (b,l) element; reductions via __shfl_xor(1,2,4).

#define SSQ_ALPHA (-300.0f)

__global__ __launch_bounds__(256) void ssq_kernel(
    const float* __restrict__ x,      // n elements (B*L)
    const float* __restrict__ bins,   // K = 32
    float* __restrict__ soft,         // n*32
    float* __restrict__ code,         // n
    int n)
{
    const int sub = threadIdx.x & 7;                 // which float4 of the 32 k's
    const float4 b4 = reinterpret_cast<const float4*>(bins)[sub];

    float4* __restrict__ soft4 = reinterpret_cast<float4*>(soft);

    const int total_vec = n * 8;                     // float4 count in soft
    const int stride = gridDim.x * blockDim.x;
    for (int f = blockIdx.x * blockDim.x + threadIdx.x; f < total_vec; f += stride) {
        const int i = f >> 3;                        // element index
        const float xv = x[i];

        // scores s_k = ALPHA * |x - b_k|  (ALPHA < 0 -> max s = nearest bin)
        float s0 = SSQ_ALPHA * fabsf(xv - b4.x);
        float s1 = SSQ_ALPHA * fabsf(xv - b4.y);
        float s2 = SSQ_ALPHA * fabsf(xv - b4.z);
        float s3 = SSQ_ALPHA * fabsf(xv - b4.w);

        // max over the 32 k's: local 4, then across the 8-lane group
        float m = fmaxf(fmaxf(s0, s1), fmaxf(s2, s3));
        m = fmaxf(m, __shfl_xor(m, 1));
        m = fmaxf(m, __shfl_xor(m, 2));
        m = fmaxf(m, __shfl_xor(m, 4));

        float e0 = __expf(s0 - m);
        float e1 = __expf(s1 - m);
        float e2 = __expf(s2 - m);
        float e3 = __expf(s3 - m);

        float sum = (e0 + e1) + (e2 + e3);
        sum += __shfl_xor(sum, 1);
        sum += __shfl_xor(sum, 2);
        sum += __shfl_xor(sum, 4);

        const float inv = __builtin_amdgcn_rcpf(sum);
        float4 w;
        w.x = e0 * inv; w.y = e1 * inv; w.z = e2 * inv; w.w = e3 * inv;
        soft4[f] = w;                                 // coalesced 16B/lane

        // code = sum_k w_k * b_k
        float c = (w.x * b4.x + w.y * b4.y) + (w.z * b4.z + w.w * b4.w);
        c += __shfl_xor(c, 1);
        c += __shfl_xor(c, 2);
        c += __shfl_xor(c, 4);
        if (sub == 0) code[i] = c;
    }
}

extern "C" void kernel_launch(void* const* d_in, const int* in_sizes, int n_in,
                              void* d_out, int out_size, void* d_ws, size_t ws_size,
                              hipStream_t stream) {
    const float* x    = (const float*)d_in[0];   // (B, L, 1) f32
    const float* bins = (const float*)d_in[1];   // (K,) f32, K == 32
    const int n = in_sizes[0];                   // B*L

    float* soft = (float*)d_out;                 // (B, L, 32)
    float* code = soft + (size_t)n * 32;         // (B, L, 1)

    const int block = 256;
    const int grid  = 2048;                      // grid-stride, ~8 blk/CU
    ssq_kernel<<<grid, block, 0, stream>>>(x, bins, soft, code, n);
}

// Round 4
// 61.121 us; speedup vs baseline: 1.0681x; 1.0681x over previous
//
#include <hip/hip_runtime.h>

// softmax(ALPHA*|x-bins|) over K=32 bins + weighted-sum code.
// Memory-bound: ~285 MB traffic, floor ~41-45us at memset-observed ~7 TB/s.
// R3: NO nontemporal ops (they broke post-timing readback coherence).
//     Cross-lane 8-wide reductions via DPP (quad_perm xor1/xor2 +
//     row_half_mirror) on the VALU pipe instead of ds_swizzle shuffles --
//     removes the serial LDS-pipe latency chain. Exact-cover 4-way ILP.

#define SSQ_SCALE (-432.80854f)   // ALPHA * log2(e) = -300 * 1.4426950408889634
#define SSQ_UNROLL 4

typedef float f32x4 __attribute__((ext_vector_type(4)));

// DPP lane-exchange within a row; all our groups are 8-lane aligned.
template <int CTRL>
__device__ __forceinline__ float dpp_f(float v) {
    int i = __builtin_bit_cast(int, v);
    i = __builtin_amdgcn_update_dpp(i, i, CTRL, 0xf, 0xf, true);
    return __builtin_bit_cast(float, i);
}
#define DPP_XOR1  0xB1   // quad_perm [1,0,3,2]
#define DPP_XOR2  0x4E   // quad_perm [2,3,0,1]
#define DPP_HMIRR 0x141  // row_half_mirror: lane i <-> 7-i within each 8

__device__ __forceinline__ float red8_max(float v) {
    v = fmaxf(v, dpp_f<DPP_XOR1>(v));
    v = fmaxf(v, dpp_f<DPP_XOR2>(v));
    v = fmaxf(v, dpp_f<DPP_HMIRR>(v));
    return v;
}
__device__ __forceinline__ float red8_sum(float v) {
    v += dpp_f<DPP_XOR1>(v);
    v += dpp_f<DPP_XOR2>(v);
    v += dpp_f<DPP_HMIRR>(v);
    return v;
}

__global__ __launch_bounds__(256) void ssq_kernel(
    const float* __restrict__ x,      // n elements (B*L)
    const float* __restrict__ bins,   // K = 32
    float* __restrict__ soft,         // n*32
    float* __restrict__ code,         // n
    int total_vec)                    // n*8 float4s
{
    const int sub = threadIdx.x & 7;                 // which float4 of the 32 k's
    const f32x4 b4 = reinterpret_cast<const f32x4*>(bins)[sub];
    f32x4* __restrict__ soft4 = reinterpret_cast<f32x4*>(soft);

    const int base = blockIdx.x * (256 * SSQ_UNROLL) + threadIdx.x;

    int   f[SSQ_UNROLL];
    bool  act[SSQ_UNROLL];
    float xv[SSQ_UNROLL];

    // Issue all loads first (MLP). total_vec % 8 == 0 -> act uniform within
    // each 8-lane group, so the DPP exchanges below stay within active lanes.
    #pragma unroll
    for (int u = 0; u < SSQ_UNROLL; ++u) {
        f[u] = base + u * 256;
        act[u] = f[u] < total_vec;
        xv[u] = act[u] ? x[f[u] >> 3] : 0.0f;
    }

    #pragma unroll
    for (int u = 0; u < SSQ_UNROLL; ++u) {
        if (!act[u]) continue;
        const float xu = xv[u];

        // scores s_k = SCALE * |x - b_k|   (SCALE<0 -> max s = nearest bin)
        float s0 = SSQ_SCALE * fabsf(xu - b4.x);
        float s1 = SSQ_SCALE * fabsf(xu - b4.y);
        float s2 = SSQ_SCALE * fabsf(xu - b4.z);
        float s3 = SSQ_SCALE * fabsf(xu - b4.w);

        // max over the 32 k's: local 4, then 8-lane DPP butterfly
        float m = red8_max(fmaxf(fmaxf(s0, s1), fmaxf(s2, s3)));

        float e0 = exp2f(s0 - m);
        float e1 = exp2f(s1 - m);
        float e2 = exp2f(s2 - m);
        float e3 = exp2f(s3 - m);

        // joint reduction: denominator and weighted-bin numerator
        float sum = red8_sum((e0 + e1) + (e2 + e3));
        float num = red8_sum((e0 * b4.x + e1 * b4.y) + (e2 * b4.z + e3 * b4.w));

        const float inv = __builtin_amdgcn_rcpf(sum);
        f32x4 w;
        w.x = e0 * inv; w.y = e1 * inv; w.z = e2 * inv; w.w = e3 * inv;
        soft4[f[u]] = w;                              // coalesced 16B/lane

        if (sub == 0) code[f[u] >> 3] = num * inv;
    }
}

extern "C" void kernel_launch(void* const* d_in, const int* in_sizes, int n_in,
                              void* d_out, int out_size, void* d_ws, size_t ws_size,
                              hipStream_t stream) {
    const float* x    = (const float*)d_in[0];   // (B, L, 1) f32
    const float* bins = (const float*)d_in[1];   // (K,) f32, K == 32
    const int n = in_sizes[0];                   // B*L

    float* soft = (float*)d_out;                 // (B, L, 32)
    float* code = soft + (size_t)n * 32;         // (B, L, 1)

    const int total_vec = n * 8;                 // float4 count of soft
    const int block = 256;
    const int grid  = (total_vec + block * SSQ_UNROLL - 1) / (block * SSQ_UNROLL);
    ssq_kernel<<<grid, block, 0, stream>>>(x, bins, soft, code, total_vec);
}